// Round 1
// baseline (526.371 us; speedup 1.0000x reference)
//
#include <hip/hip_runtime.h>
#include <hip/hip_bf16.h>
#include <math.h>

#define HW 6400
#define NT 256
#define PT 25  // elements per thread (6400/256)

__device__ __forceinline__ uint32_t f2key(float f) {
  uint32_t u = __float_as_uint(f);
  return (u & 0x80000000u) ? ~u : (u | 0x80000000u);
}
__device__ __forceinline__ float key2f(uint32_t k) {
  uint32_t u = (k & 0x80000000u) ? (k & 0x7fffffffu) : ~k;
  return __uint_as_float(u);
}

// One block per (b,c) row. Computes mean, max, and the 5 quintile-segment
// means of the sorted row via exact radix-select (keys live in registers).
__global__ __launch_bounds__(NT) void rowstats_kernel(
    const float* __restrict__ x, float* __restrict__ stacked, int C) {
  const int row = blockIdx.x;
  const int tid = threadIdx.x;
  const int lane = tid & 63;
  const int wid = tid >> 6;
  const float* xr = x + (size_t)row * HW;

  __shared__ uint32_t s_hist[256];
  __shared__ uint32_t s_wsum[4];
  __shared__ uint32_t s_selbin, s_selbelow;
  __shared__ uint32_t s_selbin4[4], s_selbelow4[4];
  __shared__ float s_red[4][8];
  __shared__ float s_tot, s_mx;

  // ---- Phase A: load (float4-vectorized), key transform, sum+max ----
  uint32_t key[PT];
  float lsum = 0.f, lmax = -INFINITY;
  const float4* xr4 = (const float4*)xr;
#pragma unroll
  for (int j = 0; j < 6; ++j) {
    float4 v4 = xr4[tid + j * NT];
    float vv[4] = {v4.x, v4.y, v4.z, v4.w};
#pragma unroll
    for (int k = 0; k < 4; ++k) {
      lsum += vv[k];
      lmax = fmaxf(lmax, vv[k]);
      key[j * 4 + k] = f2key(vv[k]);
    }
  }
  {
    float v = xr[6144 + tid];
    lsum += v;
    lmax = fmaxf(lmax, v);
    key[24] = f2key(v);
  }
#pragma unroll
  for (int off = 32; off; off >>= 1) {
    lsum += __shfl_down(lsum, off);
    lmax = fmaxf(lmax, __shfl_down(lmax, off));
  }
  if (lane == 0) { s_red[wid][0] = lsum; s_red[wid][1] = lmax; }
  __syncthreads();
  if (tid == 0) {
    s_tot = s_red[0][0] + s_red[1][0] + s_red[2][0] + s_red[3][0];
    s_mx = fmaxf(fmaxf(s_red[0][1], s_red[1][1]), fmaxf(s_red[2][1], s_red[3][1]));
  }

  // ---- Phase B: radix select, 4 target ranks (0-indexed) ----
  uint32_t rr[4], pfx[4];
#pragma unroll
  for (int t = 0; t < 4; ++t) rr[t] = 1280u * (t + 1) - 1u;

  // Round 1 (top byte), shared across all 4 targets.
  s_hist[tid] = 0;
  __syncthreads();
#pragma unroll
  for (int i = 0; i < PT; ++i) atomicAdd(&s_hist[key[i] >> 24], 1u);
  __syncthreads();
  {
    uint32_t h = s_hist[tid];
    uint32_t inc = h;
#pragma unroll
    for (int off = 1; off < 64; off <<= 1) {
      uint32_t v = __shfl_up(inc, (unsigned)off);
      if (lane >= off) inc += v;
    }
    if (lane == 63) s_wsum[wid] = inc;
    __syncthreads();
    uint32_t base = 0;
    for (int w = 0; w < 4; ++w) if (w < wid) base += s_wsum[w];
    inc += base;
    uint32_t excl = inc - h;
#pragma unroll
    for (int t = 0; t < 4; ++t)
      if (rr[t] >= excl && rr[t] < inc) { s_selbin4[t] = (uint32_t)tid; s_selbelow4[t] = excl; }
  }
  __syncthreads();
#pragma unroll
  for (int t = 0; t < 4; ++t) { pfx[t] = s_selbin4[t] << 24; rr[t] -= s_selbelow4[t]; }

  // Rounds 2..4 per target (few matching elements -> cheap).
  for (int t = 0; t < 4; ++t) {
    for (int shift = 16; shift >= 0; shift -= 8) {
      const uint32_t himask = ~((1u << (shift + 8)) - 1u);
      s_hist[tid] = 0;
      __syncthreads();
#pragma unroll
      for (int i = 0; i < PT; ++i)
        if ((key[i] & himask) == pfx[t])
          atomicAdd(&s_hist[(key[i] >> shift) & 255u], 1u);
      __syncthreads();
      uint32_t h = s_hist[tid];
      uint32_t inc = h;
#pragma unroll
      for (int off = 1; off < 64; off <<= 1) {
        uint32_t v = __shfl_up(inc, (unsigned)off);
        if (lane >= off) inc += v;
      }
      if (lane == 63) s_wsum[wid] = inc;
      __syncthreads();
      uint32_t base = 0;
      for (int w = 0; w < 4; ++w) if (w < wid) base += s_wsum[w];
      inc += base;
      uint32_t excl = inc - h;
      if (rr[t] >= excl && rr[t] < inc) { s_selbin = (uint32_t)tid; s_selbelow = excl; }
      __syncthreads();
      pfx[t] |= s_selbin << shift;
      rr[t] -= s_selbelow;
      // no barrier needed: next pass's zero+barrier orders s_selbin reuse
    }
  }

  // ---- Phase C: count/sum below each threshold (exact prefix sums) ----
  float sless[4] = {0.f, 0.f, 0.f, 0.f};
  float cless[4] = {0.f, 0.f, 0.f, 0.f};
#pragma unroll
  for (int i = 0; i < PT; ++i) {
    float v = key2f(key[i]);
#pragma unroll
    for (int t = 0; t < 4; ++t)
      if (key[i] < pfx[t]) { sless[t] += v; cless[t] += 1.f; }
  }
#pragma unroll
  for (int off = 32; off; off >>= 1) {
#pragma unroll
    for (int t = 0; t < 4; ++t) {
      sless[t] += __shfl_down(sless[t], off);
      cless[t] += __shfl_down(cless[t], off);
    }
  }
  __syncthreads();  // protect s_red reuse (phase A values already consumed)
  if (lane == 0) {
#pragma unroll
    for (int t = 0; t < 4; ++t) { s_red[wid][t] = sless[t]; s_red[wid][4 + t] = cless[t]; }
  }
  __syncthreads();
  if (tid == 0) {
    const float tot = s_tot, mx = s_mx;
    const int b = row / C, c = row % C;
    float* dst = stacked + ((size_t)b * 7) * C + c;
    dst[0] = tot * (1.f / 6400.f);
    dst[C] = mx;
    float prev = 0.f;
#pragma unroll
    for (int t = 0; t < 4; ++t) {
      float sl = s_red[0][t] + s_red[1][t] + s_red[2][t] + s_red[3][t];
      float cl = s_red[0][4 + t] + s_red[1][4 + t] + s_red[2][4 + t] + s_red[3][4 + t];
      float tval = key2f(pfx[t]);
      float kk = 1280.f * (float)(t + 1);
      float pref = sl + (kk - cl) * tval;
      dst[(size_t)(2 + t) * C] = (pref - prev) * (1.f / 1280.f);
      prev = pref;
    }
    dst[(size_t)6 * C] = (tot - prev) * (1.f / 1280.f);
  }
}

// One block per batch element: h = relu(stacked @ W1^T); g = sum_n w7[n]*h[n];
// out[c] = sigmoid(dot(g, W2[c,:]) + bias)
__global__ __launch_bounds__(256) void mlp_kernel(
    const float* __restrict__ stacked, const float* __restrict__ W1,
    const float* __restrict__ W2, const float* __restrict__ w7,
    const float* __restrict__ bias, float* __restrict__ out) {
  const int b = blockIdx.x;
  const int tid = threadIdx.x;
  __shared__ float s_stk[7 * 512];
  __shared__ float s_g[32];
  const float* src = stacked + (size_t)b * 7 * 512;
  for (int i = tid; i < 7 * 512; i += 256) s_stk[i] = src[i];
  if (tid < 32) s_g[tid] = 0.f;
  __syncthreads();
  if (tid < 224) {
    const int n = tid >> 5, r = tid & 31;
    float acc = 0.f;
    for (int c = 0; c < 512; ++c) acc = fmaf(s_stk[n * 512 + c], W1[r * 512 + c], acc);
    acc = fmaxf(acc, 0.f);
    atomicAdd(&s_g[r], w7[n] * acc);
  }
  __syncthreads();
  const float bv = bias[0];
  for (int c = tid; c < 512; c += 256) {
    float acc = bv;
#pragma unroll
    for (int r = 0; r < 32; ++r) acc = fmaf(s_g[r], W2[c * 32 + r], acc);
    out[b * 512 + c] = 1.f / (1.f + expf(-acc));
  }
}

extern "C" void kernel_launch(void* const* d_in, const int* in_sizes, int n_in,
                              void* d_out, int out_size, void* d_ws, size_t ws_size,
                              hipStream_t stream) {
  const float* x = (const float*)d_in[0];
  const float* W1 = (const float*)d_in[1];
  const float* W2 = (const float*)d_in[2];
  const float* w7 = (const float*)d_in[3];
  const float* bb = (const float*)d_in[4];
  float* out = (float*)d_out;
  float* stacked = (float*)d_ws;  // needs 32*7*512*4 = 458752 bytes

  const int B = 32, C = 512;
  rowstats_kernel<<<B * C, NT, 0, stream>>>(x, stacked, C);
  mlp_kernel<<<B, 256, 0, stream>>>(stacked, W1, W2, w7, bb, out);
}

// Round 2
// 307.592 us; speedup vs baseline: 1.7113x; 1.7113x over previous
//
#include <hip/hip_runtime.h>
#include <hip/hip_bf16.h>
#include <math.h>

#define HW 6400
#define NT 256
#define PT 25  // elements per thread (6400/256)

__device__ __forceinline__ uint32_t f2key(float f) {
  uint32_t u = __float_as_uint(f);
  return (u & 0x80000000u) ? ~u : (u | 0x80000000u);
}
__device__ __forceinline__ float key2f(uint32_t k) {
  uint32_t u = (k & 0x80000000u) ? (k & 0x7fffffffu) : ~k;
  return __uint_as_float(u);
}

// One block per (b,c) row. mean, max, and 5 quintile-segment means of the
// sorted row via value-bucket select (exact; keys stay in registers).
__global__ __launch_bounds__(NT) void rowstats_kernel(
    const float* __restrict__ x, float* __restrict__ stacked) {
  const int tid = threadIdx.x;
  const int lane = tid & 63;
  const int wid = tid >> 6;
  const int row = blockIdx.x;
  const float* xr = x + (size_t)row * HW;

  __shared__ uint32_t s_cnt[4][256];   // L1: per-wave private; L2/L3: per-target
  __shared__ uint32_t s_kmin[4][256];
  __shared__ uint32_t s_kmax[4][256];
  __shared__ uint32_t s_wsum[4][4];
  __shared__ float s_red[4][8];
  __shared__ float s_tot, s_gmx, s_gmn;
  __shared__ uint32_t s_rr[4];
  __shared__ int s_b1[4];
  __shared__ uint32_t s_klo[4], s_khi[4];
  __shared__ float s_vlo[4], s_vhi[4];
  __shared__ int s_done[4];
  __shared__ float s_tval[4];
  __shared__ int s_selbin[4];
  __shared__ uint32_t s_selexcl[4];

  // ---------- Phase A: vectorized load + sum/max/min reduce ----------
  float v[PT];
  {
    const float4* xr4 = (const float4*)xr;
#pragma unroll
    for (int j = 0; j < 6; ++j) {
      float4 q = xr4[tid + j * NT];
      v[j * 4 + 0] = q.x; v[j * 4 + 1] = q.y;
      v[j * 4 + 2] = q.z; v[j * 4 + 3] = q.w;
    }
    v[24] = xr[6144 + tid];
  }
  float lsum = 0.f, lmx = -INFINITY, lmn = INFINITY;
#pragma unroll
  for (int i = 0; i < PT; ++i) {
    lsum += v[i]; lmx = fmaxf(lmx, v[i]); lmn = fminf(lmn, v[i]);
  }
#pragma unroll
  for (int off = 32; off; off >>= 1) {
    lsum += __shfl_down(lsum, off);
    lmx = fmaxf(lmx, __shfl_down(lmx, off));
    lmn = fminf(lmn, __shfl_down(lmn, off));
  }
  if (lane == 0) { s_red[wid][0] = lsum; s_red[wid][1] = lmx; s_red[wid][2] = lmn; }
  __syncthreads();
  if (tid == 0) {
    s_tot = s_red[0][0] + s_red[1][0] + s_red[2][0] + s_red[3][0];
    s_gmx = fmaxf(fmaxf(s_red[0][1], s_red[1][1]), fmaxf(s_red[2][1], s_red[3][1]));
    s_gmn = fminf(fminf(s_red[0][2], s_red[1][2]), fminf(s_red[2][2], s_red[3][2]));
  }
#pragma unroll
  for (int w = 0; w < 4; ++w) s_cnt[w][tid] = 0;  // zero L1 per-wave hists
  if (tid < 4) s_done[tid] = 0;
  __syncthreads();

  float* dst = stacked + ((size_t)(row >> 9) * 7) * 512 + (row & 511);
  const float gmn = s_gmn, gmx = s_gmx, tot = s_tot;
  if (gmx == gmn) {  // degenerate row: all values equal
    if (tid == 0) {
      dst[0] = tot * (1.f / 6400.f);
      dst[512] = gmx;
#pragma unroll
      for (int t = 0; t < 5; ++t) dst[(size_t)(2 + t) * 512] = gmx;
    }
    return;
  }

  // ---------- L1: 256 value-buckets, per-wave private counts ----------
  const float lo1 = gmn;
  const float scale1 = 256.0f / (gmx - gmn);
#pragma unroll
  for (int i = 0; i < PT; ++i) {
    float f = (v[i] - lo1) * scale1;
    int b1 = (int)fminf(fmaxf(f, 0.0f), 255.0f);
    atomicAdd(&s_cnt[wid][b1], 1u);
  }
  __syncthreads();
  {  // scan (combine 4 wave-private hists) + select crossing bucket per target
    uint32_t h = s_cnt[0][tid] + s_cnt[1][tid] + s_cnt[2][tid] + s_cnt[3][tid];
    uint32_t inc = h;
#pragma unroll
    for (int off = 1; off < 64; off <<= 1) {
      uint32_t u = __shfl_up(inc, off);
      if (lane >= off) inc += u;
    }
    if (lane == 63) s_wsum[0][wid] = inc;
    __syncthreads();
    uint32_t base = 0;
#pragma unroll
    for (int w = 0; w < 4; ++w) if (w < wid) base += s_wsum[0][w];
    inc += base;
    uint32_t excl = inc - h;
#pragma unroll
    for (int t = 0; t < 4; ++t) {
      uint32_t r = 1280u * (t + 1) - 1u;
      if (r >= excl && r < inc) { s_b1[t] = tid; s_rr[t] = r - excl; }
    }
  }
  // zero per-target arrays for L2 (own column -> no race with scan reads)
#pragma unroll
  for (int t = 0; t < 4; ++t) {
    s_cnt[t][tid] = 0; s_kmin[t][tid] = 0xFFFFFFFFu; s_kmax[t][tid] = 0u;
  }
  __syncthreads();

  // ---------- L2: refine all 4 targets in parallel (geometric sub-split) ----------
  {
    const float w1 = (gmx - gmn) * (1.0f / 256.0f);
    const float scale2 = 256.0f / w1;
    int b1v[4]; float lo2[4];
#pragma unroll
    for (int t = 0; t < 4; ++t) { b1v[t] = s_b1[t]; lo2[t] = lo1 + (float)s_b1[t] * w1; }
#pragma unroll
    for (int i = 0; i < PT; ++i) {
      float f = (v[i] - lo1) * scale1;
      int b1 = (int)fminf(fmaxf(f, 0.0f), 255.0f);
#pragma unroll
      for (int t = 0; t < 4; ++t) {
        if (b1 == b1v[t]) {
          float f2 = (v[i] - lo2[t]) * scale2;
          int b2 = (int)fminf(fmaxf(f2, 0.0f), 255.0f);
          uint32_t k = f2key(v[i]);
          atomicAdd(&s_cnt[t][b2], 1u);
          atomicMin(&s_kmin[t][b2], k);
          atomicMax(&s_kmax[t][b2], k);
        }
      }
    }
  }
  __syncthreads();
  {  // 4 parallel scans + select
    uint32_t h[4], inc[4];
#pragma unroll
    for (int t = 0; t < 4; ++t) { h[t] = s_cnt[t][tid]; inc[t] = h[t]; }
#pragma unroll
    for (int off = 1; off < 64; off <<= 1) {
#pragma unroll
      for (int t = 0; t < 4; ++t) {
        uint32_t u = __shfl_up(inc[t], off);
        if (lane >= off) inc[t] += u;
      }
    }
    if (lane == 63) {
#pragma unroll
      for (int t = 0; t < 4; ++t) s_wsum[t][wid] = inc[t];
    }
    __syncthreads();
#pragma unroll
    for (int t = 0; t < 4; ++t) {
      uint32_t base = 0;
#pragma unroll
      for (int w = 0; w < 4; ++w) if (w < wid) base += s_wsum[t][w];
      uint32_t I = inc[t] + base, E = I - h[t];
      uint32_t r = s_rr[t];
      if (r >= E && r < I) { s_selbin[t] = tid; s_selexcl[t] = E; }
    }
  }
  __syncthreads();
  if (tid < 4) {  // resolve
    const int t = tid, b = s_selbin[t];
    uint32_t mn = s_kmin[t][b], mx2 = s_kmax[t][b];
    s_rr[t] -= s_selexcl[t];
    if (mn == mx2) { s_done[t] = 1; s_tval[t] = key2f(mn); }
    else { s_klo[t] = mn; s_khi[t] = mx2; s_vlo[t] = key2f(mn); s_vhi[t] = key2f(mx2); }
  }
  __syncthreads();

  // ---------- L3: adaptive key-space refinement (rarely >1 iteration) ----------
  for (;;) {
    int nd = s_done[0] + s_done[1] + s_done[2] + s_done[3];
    if (nd == 4) break;
#pragma unroll
    for (int t = 0; t < 4; ++t) {
      s_cnt[t][tid] = 0; s_kmin[t][tid] = 0xFFFFFFFFu; s_kmax[t][tid] = 0u;
    }
    __syncthreads();
    int act[4]; float flo[4], fhi[4], fsc[4]; uint32_t klo[4];
#pragma unroll
    for (int t = 0; t < 4; ++t) {
      act[t] = !s_done[t];
      flo[t] = s_vlo[t]; fhi[t] = s_vhi[t]; klo[t] = s_klo[t];
      fsc[t] = act[t] ? 256.0f / (float)(s_khi[t] - s_klo[t]) : 0.f;
    }
#pragma unroll
    for (int i = 0; i < PT; ++i) {
      float vi = v[i];
#pragma unroll
      for (int t = 0; t < 4; ++t) {
        if (act[t] && vi >= flo[t] && vi <= fhi[t]) {
          uint32_t k = f2key(vi);
          float f = (float)(k - klo[t]) * fsc[t];
          int b = (int)fminf(f, 255.0f);
          atomicAdd(&s_cnt[t][b], 1u);
          atomicMin(&s_kmin[t][b], k);
          atomicMax(&s_kmax[t][b], k);
        }
      }
    }
    __syncthreads();
    {  // scans + select (identical to L2)
      uint32_t h[4], inc[4];
#pragma unroll
      for (int t = 0; t < 4; ++t) { h[t] = s_cnt[t][tid]; inc[t] = h[t]; }
#pragma unroll
      for (int off = 1; off < 64; off <<= 1) {
#pragma unroll
        for (int t = 0; t < 4; ++t) {
          uint32_t u = __shfl_up(inc[t], off);
          if (lane >= off) inc[t] += u;
        }
      }
      if (lane == 63) {
#pragma unroll
        for (int t = 0; t < 4; ++t) s_wsum[t][wid] = inc[t];
      }
      __syncthreads();
#pragma unroll
      for (int t = 0; t < 4; ++t) {
        uint32_t base = 0;
#pragma unroll
        for (int w = 0; w < 4; ++w) if (w < wid) base += s_wsum[t][w];
        uint32_t I = inc[t] + base, E = I - h[t];
        uint32_t r = s_rr[t];
        if (r >= E && r < I) { s_selbin[t] = tid; s_selexcl[t] = E; }
      }
    }
    __syncthreads();
    if (tid < 4 && !s_done[tid]) {
      const int t = tid, b = s_selbin[t];
      uint32_t mn = s_kmin[t][b], mx2 = s_kmax[t][b];
      s_rr[t] -= s_selexcl[t];
      if (mn == mx2) { s_done[t] = 1; s_tval[t] = key2f(mn); }
      else { s_klo[t] = mn; s_khi[t] = mx2; s_vlo[t] = key2f(mn); s_vhi[t] = key2f(mx2); }
    }
    __syncthreads();
  }

  // ---------- Phase C: exact prefix sums below each threshold ----------
  float tv[4];
#pragma unroll
  for (int t = 0; t < 4; ++t) tv[t] = s_tval[t];
  float sless[4] = {0.f, 0.f, 0.f, 0.f};
  float cless[4] = {0.f, 0.f, 0.f, 0.f};
#pragma unroll
  for (int i = 0; i < PT; ++i) {
    float vi = v[i];
#pragma unroll
    for (int t = 0; t < 4; ++t)
      if (vi < tv[t]) { sless[t] += vi; cless[t] += 1.f; }
  }
#pragma unroll
  for (int off = 32; off; off >>= 1) {
#pragma unroll
    for (int t = 0; t < 4; ++t) {
      sless[t] += __shfl_down(sless[t], off);
      cless[t] += __shfl_down(cless[t], off);
    }
  }
  __syncthreads();
  if (lane == 0) {
#pragma unroll
    for (int t = 0; t < 4; ++t) { s_red[wid][t] = sless[t]; s_red[wid][4 + t] = cless[t]; }
  }
  __syncthreads();
  if (tid == 0) {
    dst[0] = tot * (1.f / 6400.f);
    dst[512] = gmx;
    float prev = 0.f;
#pragma unroll
    for (int t = 0; t < 4; ++t) {
      float sl = s_red[0][t] + s_red[1][t] + s_red[2][t] + s_red[3][t];
      float cl = s_red[0][4 + t] + s_red[1][4 + t] + s_red[2][4 + t] + s_red[3][4 + t];
      float kk = 1280.f * (float)(t + 1);
      float pref = sl + (kk - cl) * tv[t];
      dst[(size_t)(2 + t) * 512] = (pref - prev) * (1.f / 1280.f);
      prev = pref;
    }
    dst[(size_t)6 * 512] = (tot - prev) * (1.f / 1280.f);
  }
}

// One block per batch element: h = relu(stacked @ W1^T); g = sum_n w7[n]*h[n];
// out[c] = sigmoid(dot(g, W2[c,:]) + bias)
__global__ __launch_bounds__(256) void mlp_kernel(
    const float* __restrict__ stacked, const float* __restrict__ W1,
    const float* __restrict__ W2, const float* __restrict__ w7,
    const float* __restrict__ bias, float* __restrict__ out) {
  const int b = blockIdx.x;
  const int tid = threadIdx.x;
  __shared__ float s_stk[7 * 512];
  __shared__ float s_g[32];
  const float* src = stacked + (size_t)b * 7 * 512;
  for (int i = tid; i < 7 * 512; i += 256) s_stk[i] = src[i];
  if (tid < 32) s_g[tid] = 0.f;
  __syncthreads();
  if (tid < 224) {
    const int n = tid >> 5, r = tid & 31;
    float acc = 0.f;
    for (int c = 0; c < 512; ++c) acc = fmaf(s_stk[n * 512 + c], W1[r * 512 + c], acc);
    acc = fmaxf(acc, 0.f);
    atomicAdd(&s_g[r], w7[n] * acc);
  }
  __syncthreads();
  const float bv = bias[0];
  for (int c = tid; c < 512; c += 256) {
    float acc = bv;
#pragma unroll
    for (int r = 0; r < 32; ++r) acc = fmaf(s_g[r], W2[c * 32 + r], acc);
    out[b * 512 + c] = 1.f / (1.f + expf(-acc));
  }
}

extern "C" void kernel_launch(void* const* d_in, const int* in_sizes, int n_in,
                              void* d_out, int out_size, void* d_ws, size_t ws_size,
                              hipStream_t stream) {
  const float* x = (const float*)d_in[0];
  const float* W1 = (const float*)d_in[1];
  const float* W2 = (const float*)d_in[2];
  const float* w7 = (const float*)d_in[3];
  const float* bb = (const float*)d_in[4];
  float* out = (float*)d_out;
  float* stacked = (float*)d_ws;  // 32*7*512*4 = 458752 bytes

  rowstats_kernel<<<32 * 512, NT, 0, stream>>>(x, stacked);
  mlp_kernel<<<32, 256, 0, stream>>>(stacked, W1, W2, w7, bb, out);
}

// Round 3
// 108.866 us; speedup vs baseline: 4.8350x; 2.8254x over previous
//
#include <hip/hip_runtime.h>
#include <hip/hip_bf16.h>
#include <math.h>

#define HW 6400
#define NT 256
#define PT 25        // elements per thread
#define NB 2048      // value buckets
#define BPT (NB/NT)  // buckets per thread (8)

// packed bucket entry: bits 48+ = count, bits 0..47 = sum of (v*2^24 + 2^30)
__device__ __forceinline__ double fixval(unsigned long long p) {
  unsigned long long cnt = p >> 48;
  long long fs = (long long)(p & 0xFFFFFFFFFFFFULL) - ((long long)cnt << 30);
  return (double)fs * (1.0 / 16777216.0);
}

// One block per (b,c) row. mean, max, and the 5 quintile-segment means of the
// sorted row via a single count+sum histogram pass (deterministic int atomics).
__global__ __launch_bounds__(NT) void rowstats_kernel(
    const float* __restrict__ x, float* __restrict__ stacked) {
  const int tid = threadIdx.x;
  const int lane = tid & 63;
  const int wid = tid >> 6;
  const int row = blockIdx.x;
  const float* xr = x + (size_t)row * HW;

  __shared__ unsigned long long s_hist[NB];  // 16 KB
  __shared__ float s_mnw[4], s_mxw[4];
  __shared__ unsigned long long s_wtot[4];
  __shared__ int s_cb[4];
  __shared__ unsigned long long s_cE[4];

  // ---- Phase A: vectorized load, min/max reduce; zero histogram ----
  float v[PT];
  {
    const float4* xr4 = (const float4*)xr;
#pragma unroll
    for (int j = 0; j < 6; ++j) {
      float4 q = xr4[tid + j * NT];
      v[4 * j + 0] = q.x; v[4 * j + 1] = q.y;
      v[4 * j + 2] = q.z; v[4 * j + 3] = q.w;
    }
    v[24] = xr[6144 + tid];
  }
  float lmx = v[0], lmn = v[0];
#pragma unroll
  for (int i = 1; i < PT; ++i) { lmx = fmaxf(lmx, v[i]); lmn = fminf(lmn, v[i]); }
#pragma unroll
  for (int off = 32; off; off >>= 1) {
    lmx = fmaxf(lmx, __shfl_down(lmx, off));
    lmn = fminf(lmn, __shfl_down(lmn, off));
  }
  if (lane == 0) { s_mnw[wid] = lmn; s_mxw[wid] = lmx; }
#pragma unroll
  for (int j = 0; j < BPT; ++j) s_hist[tid * BPT + j] = 0ULL;
  __syncthreads();

  const float gmn = fminf(fminf(s_mnw[0], s_mnw[1]), fminf(s_mnw[2], s_mnw[3]));
  const float gmx = fmaxf(fmaxf(s_mxw[0], s_mxw[1]), fmaxf(s_mxw[2], s_mxw[3]));

  const int b_ = row >> 9, c_ = row & 511;
  float* dst = stacked + ((size_t)b_ * 7) * 512 + c_;

  if (!(gmx - gmn > 1e-30f)) {  // degenerate: (near-)constant row
    if (tid == 0) {
      dst[0] = gmx; dst[512] = gmx;
#pragma unroll
      for (int t = 0; t < 5; ++t) dst[(size_t)(2 + t) * 512] = gmx;
    }
    return;
  }

  // ---- L1: single count+sum histogram sweep ----
  const float scale = (float)NB / (gmx - gmn);
  const float nls = -gmn * scale;
#pragma unroll
  for (int i = 0; i < PT; ++i) {
    float f = fmaf(v[i], scale, nls);
    int b = (int)f;
    b = b < 0 ? 0 : (b > NB - 1 ? NB - 1 : b);
    int q = (int)(v[i] * 16777216.0f) + (1 << 30);
    atomicAdd(&s_hist[b], (1ULL << 48) + (unsigned long long)(unsigned int)q);
  }
  __syncthreads();

  // ---- Scan: thread owns 8 consecutive buckets ----
  unsigned long long h[BPT];
  unsigned long long run = 0ULL;
#pragma unroll
  for (int j = 0; j < BPT; ++j) { h[j] = s_hist[tid * BPT + j]; run += h[j]; }
  unsigned long long inc = run;
#pragma unroll
  for (int off = 1; off < 64; off <<= 1) {
    unsigned long long u = __shfl_up(inc, off);
    if (lane >= off) inc += u;
  }
  if (lane == 63) s_wtot[wid] = inc;
  __syncthreads();
  unsigned long long base = inc - run;
#pragma unroll
  for (int w = 0; w < 4; ++w) if (w < wid) base += s_wtot[w];

  // ---- Crossing-bucket detection for k = 1280,2560,3840,5120 ----
  {
    unsigned long long E = base;
#pragma unroll
    for (int j = 0; j < BPT; ++j) {
      unsigned long long I = E + h[j];
      unsigned cEc = (unsigned)(E >> 48), cIc = (unsigned)(I >> 48);
#pragma unroll
      for (int t = 0; t < 4; ++t) {
        unsigned k = 1280u * (t + 1);
        if (cEc < k && k <= cIc) { s_cb[t] = tid * BPT + j; s_cE[t] = E; }
      }
      E = I;
    }
  }
  __syncthreads();

  // ---- Resolve + write (7 outputs) ----
  if (tid == 0) {
    unsigned long long grand = s_wtot[0] + s_wtot[1] + s_wtot[2] + s_wtot[3];
    double totv = fixval(grand);
    const double width = (double)(gmx - gmn) / (double)NB;
    double pref[4];
#pragma unroll
    for (int t = 0; t < 4; ++t) {
      unsigned long long E = s_cE[t];
      unsigned cEc = (unsigned)(E >> 48);
      double sE = fixval(E);
      double mid = (double)gmn + ((double)s_cb[t] + 0.5) * width;
      double m = (double)(1280u * (t + 1) - cEc);
      pref[t] = sE + m * mid;
    }
    dst[0] = (float)(totv * (1.0 / 6400.0));
    dst[512] = gmx;
    double prev = 0.0;
#pragma unroll
    for (int t = 0; t < 4; ++t) {
      dst[(size_t)(2 + t) * 512] = (float)((pref[t] - prev) * (1.0 / 1280.0));
      prev = pref[t];
    }
    dst[(size_t)6 * 512] = (float)((totv - prev) * (1.0 / 1280.0));
  }
}

// One block per batch element: h = relu(stacked @ W1^T); g = sum_n w7[n]*h[n];
// out[c] = sigmoid(dot(g, W2[c,:]) + bias)
__global__ __launch_bounds__(256) void mlp_kernel(
    const float* __restrict__ stacked, const float* __restrict__ W1,
    const float* __restrict__ W2, const float* __restrict__ w7,
    const float* __restrict__ bias, float* __restrict__ out) {
  const int b = blockIdx.x;
  const int tid = threadIdx.x;
  __shared__ float s_stk[7 * 512];
  __shared__ float s_g[32];
  const float* src = stacked + (size_t)b * 7 * 512;
  for (int i = tid; i < 7 * 512; i += 256) s_stk[i] = src[i];
  if (tid < 32) s_g[tid] = 0.f;
  __syncthreads();
  if (tid < 224) {
    const int n = tid >> 5, r = tid & 31;
    float acc = 0.f;
    for (int c = 0; c < 512; ++c) acc = fmaf(s_stk[n * 512 + c], W1[r * 512 + c], acc);
    acc = fmaxf(acc, 0.f);
    atomicAdd(&s_g[r], w7[n] * acc);
  }
  __syncthreads();
  const float bv = bias[0];
  for (int c = tid; c < 512; c += 256) {
    float acc = bv;
#pragma unroll
    for (int r = 0; r < 32; ++r) acc = fmaf(s_g[r], W2[c * 32 + r], acc);
    out[b * 512 + c] = 1.f / (1.f + expf(-acc));
  }
}

extern "C" void kernel_launch(void* const* d_in, const int* in_sizes, int n_in,
                              void* d_out, int out_size, void* d_ws, size_t ws_size,
                              hipStream_t stream) {
  const float* x = (const float*)d_in[0];
  const float* W1 = (const float*)d_in[1];
  const float* W2 = (const float*)d_in[2];
  const float* w7 = (const float*)d_in[3];
  const float* bb = (const float*)d_in[4];
  float* out = (float*)d_out;
  float* stacked = (float*)d_ws;  // 32*7*512*4 = 458752 bytes

  rowstats_kernel<<<32 * 512, NT, 0, stream>>>(x, stacked);
  mlp_kernel<<<32, 256, 0, stream>>>(stacked, W1, W2, w7, bb, out);
}

// Round 4
// 101.150 us; speedup vs baseline: 5.2039x; 1.0763x over previous
//
#include <hip/hip_runtime.h>
#include <hip/hip_bf16.h>
#include <math.h>

#define HW 6400
#define NT 256
#define PT 25        // elements per thread
#define NB 2048      // value buckets
#define BPT (NB/NT)  // buckets per thread (8)

// One block per (b,c) row. mean, max, and the 5 quintile-segment means of the
// sorted row via a count-only histogram + analytic (midpoint) value sums.
__global__ __launch_bounds__(NT) void rowstats_kernel(
    const float* __restrict__ x, float* __restrict__ stacked) {
  const int tid = threadIdx.x;
  const int lane = tid & 63;
  const int wid = tid >> 6;
  const int row = blockIdx.x;
  const float* xr = x + (size_t)row * HW;

  __shared__ __align__(16) unsigned s_hist[NB];  // 8 KB, count-only
  __shared__ float s_mnw[4], s_mxw[4], s_smw[4];
  __shared__ unsigned long long s_wtot[4];
  __shared__ int s_cb[4];
  __shared__ unsigned long long s_cE[4];

  // ---- Phase A: vectorized load; sum/min/max reduce; zero histogram ----
  float v[PT];
  {
    const float4* xr4 = (const float4*)xr;
#pragma unroll
    for (int j = 0; j < 6; ++j) {
      float4 q = xr4[tid + j * NT];
      v[4 * j + 0] = q.x; v[4 * j + 1] = q.y;
      v[4 * j + 2] = q.z; v[4 * j + 3] = q.w;
    }
    v[24] = xr[6144 + tid];
  }
  float lmx = v[0], lmn = v[0], lsm = v[0];
#pragma unroll
  for (int i = 1; i < PT; ++i) {
    lmx = fmaxf(lmx, v[i]); lmn = fminf(lmn, v[i]); lsm += v[i];
  }
#pragma unroll
  for (int off = 32; off; off >>= 1) {
    lmx = fmaxf(lmx, __shfl_down(lmx, off));
    lmn = fminf(lmn, __shfl_down(lmn, off));
    lsm += __shfl_down(lsm, off);
  }
  if (lane == 0) { s_mnw[wid] = lmn; s_mxw[wid] = lmx; s_smw[wid] = lsm; }
  {
    uint4* z = (uint4*)&s_hist[tid * BPT];
    z[0] = make_uint4(0u, 0u, 0u, 0u);
    z[1] = make_uint4(0u, 0u, 0u, 0u);
  }
  __syncthreads();

  const float gmn = fminf(fminf(s_mnw[0], s_mnw[1]), fminf(s_mnw[2], s_mnw[3]));
  const float gmx = fmaxf(fmaxf(s_mxw[0], s_mxw[1]), fmaxf(s_mxw[2], s_mxw[3]));
  const float tot = (s_smw[0] + s_smw[1]) + (s_smw[2] + s_smw[3]);

  float* dst = stacked + ((size_t)(row >> 9) * 7) * 512 + (row & 511);

  if (!(gmx > gmn)) {  // degenerate: constant row
    if (tid == 0) {
      dst[0] = tot * (1.f / 6400.f);
      dst[512] = gmx;
#pragma unroll
      for (int t = 0; t < 5; ++t) dst[(size_t)(2 + t) * 512] = gmx;
    }
    return;
  }

  // ---- Histogram: count-only, 32-bit LDS atomics ----
  const float scale = (float)NB / (gmx - gmn);
  const float nls = -gmn * scale;
#pragma unroll
  for (int i = 0; i < PT; ++i) {
    float f = fmaf(v[i], scale, nls);
    f = fminf(fmaxf(f, 0.0f), (float)(NB - 1));  // -> v_med3_f32
    atomicAdd(&s_hist[(int)f], 1u);
  }
  __syncthreads();

  // ---- Scan of packed (count<<32 | count*bucket_index); max wsum 13.1M ----
  unsigned h[BPT];
  {
    const uint4* p = (const uint4*)&s_hist[tid * BPT];
    uint4 a = p[0], b = p[1];
    h[0] = a.x; h[1] = a.y; h[2] = a.z; h[3] = a.w;
    h[4] = b.x; h[5] = b.y; h[6] = b.z; h[7] = b.w;
  }
  unsigned long long run = 0ULL;
#pragma unroll
  for (int j = 0; j < BPT; ++j)
    run += ((unsigned long long)h[j] << 32) |
           (unsigned long long)(h[j] * (unsigned)(tid * BPT + j));
  unsigned long long inc = run;
#pragma unroll
  for (int off = 1; off < 64; off <<= 1) {
    unsigned long long u = __shfl_up(inc, off);
    if (lane >= off) inc += u;
  }
  if (lane == 63) s_wtot[wid] = inc;
  __syncthreads();
  unsigned long long E = inc - run;
#pragma unroll
  for (int w = 0; w < 4; ++w) if (w < wid) E += s_wtot[w];

  // ---- Crossing-bucket detection for k = 1280,2560,3840,5120 ----
#pragma unroll
  for (int j = 0; j < BPT; ++j) {
    unsigned long long dlt = ((unsigned long long)h[j] << 32) |
                             (unsigned long long)(h[j] * (unsigned)(tid * BPT + j));
    unsigned long long I = E + dlt;
    unsigned cE = (unsigned)(E >> 32), cI = (unsigned)(I >> 32);
#pragma unroll
    for (int t = 0; t < 4; ++t) {
      unsigned k = 1280u * (t + 1);
      if (cE < k && k <= cI) { s_cb[t] = tid * BPT + j; s_cE[t] = E; }
    }
    E = I;
  }
  __syncthreads();

  // ---- Resolve + write ----
  if (tid == 0) {
    const double w = (double)(gmx - gmn) / (double)NB;
    const double g0 = (double)gmn;
    double pref[4];
#pragma unroll
    for (int t = 0; t < 4; ++t) {
      unsigned long long Ee = s_cE[t];
      double cE = (double)(unsigned)(Ee >> 32);
      double wE = (double)(unsigned)(Ee & 0xFFFFFFFFu);
      double k = 1280.0 * (double)(t + 1);
      double m = k - cE;
      pref[t] = g0 * k + w * (wE + 0.5 * cE + m * ((double)s_cb[t] + 0.5));
    }
    dst[0] = tot * (1.f / 6400.f);
    dst[512] = gmx;
    double prev = 0.0;
    const double totd = (double)tot;
#pragma unroll
    for (int t = 0; t < 4; ++t) {
      dst[(size_t)(2 + t) * 512] = (float)((pref[t] - prev) * (1.0 / 1280.0));
      prev = pref[t];
    }
    dst[(size_t)6 * 512] = (float)((totd - prev) * (1.0 / 1280.0));
  }
}

// One block per batch element: h = relu(stacked @ W1^T); g = sum_n w7[n]*h[n];
// out[c] = sigmoid(dot(g, W2[c,:]) + bias)
__global__ __launch_bounds__(256) void mlp_kernel(
    const float* __restrict__ stacked, const float* __restrict__ W1,
    const float* __restrict__ W2, const float* __restrict__ w7,
    const float* __restrict__ bias, float* __restrict__ out) {
  const int b = blockIdx.x;
  const int tid = threadIdx.x;
  __shared__ float s_stk[7 * 512];
  __shared__ float s_g[32];
  const float* src = stacked + (size_t)b * 7 * 512;
  for (int i = tid; i < 7 * 512; i += 256) s_stk[i] = src[i];
  if (tid < 32) s_g[tid] = 0.f;
  __syncthreads();
  if (tid < 224) {
    const int n = tid >> 5, r = tid & 31;
    float acc = 0.f;
    for (int c = 0; c < 512; ++c) acc = fmaf(s_stk[n * 512 + c], W1[r * 512 + c], acc);
    acc = fmaxf(acc, 0.f);
    atomicAdd(&s_g[r], w7[n] * acc);
  }
  __syncthreads();
  const float bv = bias[0];
  for (int c = tid; c < 512; c += 256) {
    float acc = bv;
#pragma unroll
    for (int r = 0; r < 32; ++r) acc = fmaf(s_g[r], W2[c * 32 + r], acc);
    out[b * 512 + c] = 1.f / (1.f + expf(-acc));
  }
}

extern "C" void kernel_launch(void* const* d_in, const int* in_sizes, int n_in,
                              void* d_out, int out_size, void* d_ws, size_t ws_size,
                              hipStream_t stream) {
  const float* x = (const float*)d_in[0];
  const float* W1 = (const float*)d_in[1];
  const float* W2 = (const float*)d_in[2];
  const float* w7 = (const float*)d_in[3];
  const float* bb = (const float*)d_in[4];
  float* out = (float*)d_out;
  float* stacked = (float*)d_ws;  // 32*7*512*4 = 458752 bytes

  rowstats_kernel<<<32 * 512, NT, 0, stream>>>(x, stacked);
  mlp_kernel<<<32, 256, 0, stream>>>(stacked, W1, W2, w7, bb, out);
}